// Round 2
// baseline (4236.993 us; speedup 1.0000x reference)
//
#include <hip/hip_runtime.h>

// GCN: h1 = x@W1 ; agg1 = Anorm*h1 + b1 ; relu ; h2 = hr@W2 ; agg2 = Anorm*h2 + b2 ; log_softmax
// N=100000, E=3200000, F_in=512, H=16, C=7. ALL float tensors are f32 (reference dtype);
// edge_index is int32. Output is f32 [N, 7].

#define F_IN 512
#define HID  16
#define NCLS 7

__global__ __launch_bounds__(256) void k_deg(const int* __restrict__ ei, int E,
                                             float* __restrict__ deg) {
    int e = blockIdx.x * blockDim.x + threadIdx.x;
    if (e < E) atomicAdd(&deg[ei[E + e]], 1.0f);
}

__global__ __launch_bounds__(256) void k_dinv(float* __restrict__ deg, int N) {
    int i = blockIdx.x * blockDim.x + threadIdx.x;
    if (i < N) deg[i] = rsqrtf(deg[i] + 1.0f);
}

// h1[i][j] = sum_k x[i][k] * W1[k][j]; thread-per-row, W1 in LDS (f32, 32 KB).
// All lanes read the same wl address per FMA -> pure LDS broadcast, no conflicts.
__global__ __launch_bounds__(256) void k_gemm1(const float* __restrict__ x,
                                               const float* __restrict__ W1,
                                               float* __restrict__ h1, int N) {
    __shared__ float wl[F_IN * HID];  // 32 KB
    for (int t = threadIdx.x; t < F_IN * HID; t += 256) wl[t] = W1[t];
    __syncthreads();
    int row = blockIdx.x * blockDim.x + threadIdx.x;
    if (row >= N) return;
    const float* xr = x + (size_t)row * F_IN;
    float acc[HID];
#pragma unroll
    for (int j = 0; j < HID; j++) acc[j] = 0.0f;
    for (int k0 = 0; k0 < F_IN; k0 += 4) {
        float4 xv = *(const float4*)(xr + k0);
        const float* w0 = &wl[k0 * HID];
#pragma unroll
        for (int j = 0; j < HID; j++) acc[j] = fmaf(xv.x, w0[j], acc[j]);
#pragma unroll
        for (int j = 0; j < HID; j++) acc[j] = fmaf(xv.y, w0[HID + j], acc[j]);
#pragma unroll
        for (int j = 0; j < HID; j++) acc[j] = fmaf(xv.z, w0[2 * HID + j], acc[j]);
#pragma unroll
        for (int j = 0; j < HID; j++) acc[j] = fmaf(xv.w, w0[3 * HID + j], acc[j]);
    }
    float* hr = h1 + (size_t)row * HID;
#pragma unroll
    for (int j = 0; j < HID; j += 4)
        *(float4*)(hr + j) = make_float4(acc[j], acc[j + 1], acc[j + 2], acc[j + 3]);
}

template <int F>
__global__ __launch_bounds__(256) void k_agg(const int* __restrict__ ei, int E,
                                             const float* __restrict__ dinv,
                                             const float* __restrict__ h,
                                             float* __restrict__ agg) {
    int e = blockIdx.x * blockDim.x + threadIdx.x;
    if (e >= E) return;
    int s = ei[e], d = ei[E + e];
    float nrm = dinv[s] * dinv[d];
    const float* hs = h + (size_t)s * F;
    float* ad = agg + (size_t)d * F;
#pragma unroll
    for (int j = 0; j < F; j++) atomicAdd(&ad[j], nrm * hs[j]);
}

// agg1 + self-loop + b1, relu, then h2 = hr @ W2
__global__ __launch_bounds__(256) void k_post1(const float* __restrict__ agg1,
                                               const float* __restrict__ h1,
                                               const float* __restrict__ dinv,
                                               const float* __restrict__ b1,
                                               const float* __restrict__ W2,
                                               float* __restrict__ h2, int N) {
    __shared__ float w2l[HID * NCLS], b1l[HID];
    if (threadIdx.x < HID * NCLS) w2l[threadIdx.x] = W2[threadIdx.x];
    if (threadIdx.x < HID) b1l[threadIdx.x] = b1[threadIdx.x];
    __syncthreads();
    int i = blockIdx.x * blockDim.x + threadIdx.x;
    if (i >= N) return;
    float d2 = dinv[i] * dinv[i];
    float hr[HID];
#pragma unroll
    for (int j = 0; j < HID; j++) {
        float v = agg1[(size_t)i * HID + j] + d2 * h1[(size_t)i * HID + j] + b1l[j];
        hr[j] = v > 0.0f ? v : 0.0f;
    }
#pragma unroll
    for (int c = 0; c < NCLS; c++) {
        float a = 0.0f;
#pragma unroll
        for (int j = 0; j < HID; j++) a = fmaf(hr[j], w2l[j * NCLS + c], a);
        h2[(size_t)i * NCLS + c] = a;
    }
}

// agg2 + self-loop + b2, log_softmax, f32 out
__global__ __launch_bounds__(256) void k_post2(const float* __restrict__ agg2,
                                               const float* __restrict__ h2,
                                               const float* __restrict__ dinv,
                                               const float* __restrict__ b2,
                                               float* __restrict__ out, int N) {
    __shared__ float b2l[NCLS];
    if (threadIdx.x < NCLS) b2l[threadIdx.x] = b2[threadIdx.x];
    __syncthreads();
    int i = blockIdx.x * blockDim.x + threadIdx.x;
    if (i >= N) return;
    float d2 = dinv[i] * dinv[i];
    float v[NCLS], m = -1e30f;
#pragma unroll
    for (int c = 0; c < NCLS; c++) {
        v[c] = agg2[(size_t)i * NCLS + c] + d2 * h2[(size_t)i * NCLS + c] + b2l[c];
        m = fmaxf(m, v[c]);
    }
    float s = 0.0f;
#pragma unroll
    for (int c = 0; c < NCLS; c++) s += expf(v[c] - m);
    float lse = m + logf(s);
#pragma unroll
    for (int c = 0; c < NCLS; c++)
        out[(size_t)i * NCLS + c] = v[c] - lse;
}

extern "C" void kernel_launch(void* const* d_in, const int* in_sizes, int n_in,
                              void* d_out, int out_size, void* d_ws, size_t ws_size,
                              hipStream_t stream) {
    const float* x  = (const float*)d_in[0];
    const int*   ei = (const int*)d_in[1];
    const float* W1 = (const float*)d_in[2];
    const float* b1 = (const float*)d_in[3];
    const float* W2 = (const float*)d_in[4];
    const float* b2 = (const float*)d_in[5];
    float* out = (float*)d_out;

    const int N = in_sizes[0] / F_IN;     // 100000
    const int E = in_sizes[1] / 2;        // 3200000

    // ws layout (floats): [dinv N][agg1 16N][agg2 7N][h1 16N][h2 7N] = 47N floats (18.8 MB)
    float* dinv = (float*)d_ws;
    float* agg1 = dinv + N;
    float* agg2 = agg1 + (size_t)N * HID;
    float* h1   = agg2 + (size_t)N * NCLS;
    float* h2   = h1 + (size_t)N * HID;

    // zero the atomic accumulators: dinv + agg1 + agg2 = 24N floats
    hipMemsetAsync(d_ws, 0, (size_t)N * (1 + HID + NCLS) * sizeof(float), stream);

    int bE = (E + 255) / 256;
    int bN = (N + 255) / 256;

    k_deg<<<bE, 256, 0, stream>>>(ei, E, dinv);
    k_dinv<<<bN, 256, 0, stream>>>(dinv, N);
    k_gemm1<<<bN, 256, 0, stream>>>(x, W1, h1, N);
    k_agg<HID><<<bE, 256, 0, stream>>>(ei, E, dinv, h1, agg1);
    k_post1<<<bN, 256, 0, stream>>>(agg1, h1, dinv, b1, W2, h2, N);
    k_agg<NCLS><<<bE, 256, 0, stream>>>(ei, E, dinv, h2, agg2);
    k_post2<<<bN, 256, 0, stream>>>(agg2, h2, dinv, b2, out, N);
}

// Round 3
// 841.723 us; speedup vs baseline: 5.0337x; 5.0337x over previous
//
#include <hip/hip_runtime.h>
#include <math.h>

// GCN 2-layer, f32. N=100000, E=3200000, F_in=512, H=16, C=7.
// Round 3: CSR-by-dst built per call; gather aggregation (NO float atomics).
// hs1 = dinv*(x@W1) (pre-scaled) -> agg1 gather -> relu -> @W2 -> hs2 = dinv*h2
// -> agg2 gather -> +b2 -> log_softmax.

#define F_IN 512
#define HID  16
#define NCLS 7

// ---- degree count (int atomics, fire-and-forget) ----
__global__ __launch_bounds__(256) void k_deg(const int* __restrict__ ei, int E,
                                             int* __restrict__ cnt) {
    int e = blockIdx.x * blockDim.x + threadIdx.x;
    if (e < E) atomicAdd(&cnt[ei[E + e]], 1);
}

__global__ __launch_bounds__(256) void k_dinv(const int* __restrict__ cnt,
                                              float* __restrict__ dinv, int N) {
    int i = blockIdx.x * blockDim.x + threadIdx.x;
    if (i < N) dinv[i] = rsqrtf((float)cnt[i] + 1.0f);
}

// ---- exclusive scan of cnt -> offs (3 kernels: block scan, scan of sums, add) ----
__global__ __launch_bounds__(256) void k_scan_a(const int* __restrict__ cnt, int N,
                                                int* __restrict__ offs,
                                                int* __restrict__ bsum) {
    __shared__ int sd[256];
    int tid = threadIdx.x;
    int base = blockIdx.x * 1024 + tid * 4;
    int c0 = 0, c1 = 0, c2 = 0, c3 = 0;
    if (base + 0 < N) c0 = cnt[base + 0];
    if (base + 1 < N) c1 = cnt[base + 1];
    if (base + 2 < N) c2 = cnt[base + 2];
    if (base + 3 < N) c3 = cnt[base + 3];
    int tsum = c0 + c1 + c2 + c3;
    sd[tid] = tsum;
    __syncthreads();
    for (int off = 1; off < 256; off <<= 1) {
        int t = (tid >= off) ? sd[tid - off] : 0;
        __syncthreads();
        sd[tid] += t;
        __syncthreads();
    }
    int excl = sd[tid] - tsum;
    if (base + 0 < N) offs[base + 0] = excl; excl += c0;
    if (base + 1 < N) offs[base + 1] = excl; excl += c1;
    if (base + 2 < N) offs[base + 2] = excl; excl += c2;
    if (base + 3 < N) offs[base + 3] = excl;
    if (tid == 255) bsum[blockIdx.x] = sd[255];
}

__global__ __launch_bounds__(512) void k_scan_b(int* __restrict__ bsum, int nb) {
    __shared__ int sd[512];
    int tid = threadIdx.x;
    int v = (tid < nb) ? bsum[tid] : 0;
    sd[tid] = v;
    __syncthreads();
    for (int off = 1; off < 512; off <<= 1) {
        int t = (tid >= off) ? sd[tid - off] : 0;
        __syncthreads();
        sd[tid] += t;
        __syncthreads();
    }
    if (tid < nb) bsum[tid] = sd[tid] - v;  // exclusive
}

__global__ __launch_bounds__(256) void k_scan_c(int* __restrict__ offs, int N,
                                                const int* __restrict__ bsum) {
    int add = bsum[blockIdx.x];
    int base = blockIdx.x * 1024 + threadIdx.x * 4;
#pragma unroll
    for (int q = 0; q < 4; q++)
        if (base + q < N) offs[base + q] += add;
}

// ---- scatter edges into CSR (offs becomes row END after this) ----
__global__ __launch_bounds__(256) void k_scatter(const int* __restrict__ ei, int E,
                                                 int* __restrict__ offs,
                                                 int* __restrict__ csr_src) {
    int e = blockIdx.x * blockDim.x + threadIdx.x;
    if (e >= E) return;
    int s = ei[e], d = ei[E + e];
    int pos = atomicAdd(&offs[d], 1);
    csr_src[pos] = s;
}

// ---- hs1[i][j] = dinv[i] * sum_k x[i][k]*W1[k][j]; W1 in LDS, broadcast reads ----
__global__ __launch_bounds__(256) void k_gemm1(const float* __restrict__ x,
                                               const float* __restrict__ W1,
                                               const float* __restrict__ dinv,
                                               float* __restrict__ hs1, int N) {
    __shared__ float wl[F_IN * HID];  // 32 KB
    for (int t = threadIdx.x; t < F_IN * HID; t += 256) wl[t] = W1[t];
    __syncthreads();
    int row = blockIdx.x * blockDim.x + threadIdx.x;
    if (row >= N) return;
    const float* xr = x + (size_t)row * F_IN;
    float acc[HID];
#pragma unroll
    for (int j = 0; j < HID; j++) acc[j] = 0.0f;
    for (int k0 = 0; k0 < F_IN; k0 += 4) {
        float4 xv = *(const float4*)(xr + k0);
        const float* w0 = &wl[k0 * HID];
#pragma unroll
        for (int j = 0; j < HID; j++) acc[j] = fmaf(xv.x, w0[j], acc[j]);
#pragma unroll
        for (int j = 0; j < HID; j++) acc[j] = fmaf(xv.y, w0[HID + j], acc[j]);
#pragma unroll
        for (int j = 0; j < HID; j++) acc[j] = fmaf(xv.z, w0[2 * HID + j], acc[j]);
#pragma unroll
        for (int j = 0; j < HID; j++) acc[j] = fmaf(xv.w, w0[3 * HID + j], acc[j]);
    }
    float dv = dinv[row];
    float* hr = hs1 + (size_t)row * HID;
#pragma unroll
    for (int j = 0; j < HID; j += 4)
        *(float4*)(hr + j) = make_float4(dv * acc[j], dv * acc[j + 1],
                                         dv * acc[j + 2], dv * acc[j + 3]);
}

// ---- layer-1 aggregation (gather) + b1 + relu + @W2 + scale by dinv -> hs2 ----
// 16 lanes per node; lane j owns feature j. Shuffle-reduce the 16x7 matvec.
__global__ __launch_bounds__(256) void k_agg1(const int* __restrict__ csr,
                                              const int* __restrict__ offs,
                                              const int* __restrict__ cnt,
                                              const float* __restrict__ dinv,
                                              const float* __restrict__ hs1,
                                              const float* __restrict__ b1,
                                              const float* __restrict__ W2,
                                              float* __restrict__ hs2, int N) {
    int lane = threadIdx.x & 15;
    int i = blockIdx.x * 16 + (threadIdx.x >> 4);
    float w2r[NCLS];
#pragma unroll
    for (int c = 0; c < NCLS; c++) w2r[c] = W2[lane * NCLS + c];
    float b1l = b1[lane];
    if (i >= N) return;  // group-uniform (16 | grid chunking)
    int end = offs[i], cn = cnt[i], start = end - cn;
    float acc = hs1[(size_t)i * HID + lane];  // self-loop (pre-scaled)
    for (int k = start; k < end; k++) {
        int s = csr[k];
        acc += hs1[(size_t)s * HID + lane];
    }
    float v = fmaf(dinv[i], acc, b1l);
    float hr = v > 0.0f ? v : 0.0f;
    float dv = dinv[i];
    float res[NCLS];
#pragma unroll
    for (int c = 0; c < NCLS; c++) {
        float t = hr * w2r[c];
#pragma unroll
        for (int w = 8; w >= 1; w >>= 1) t += __shfl_xor(t, w, 16);
        res[c] = t;
    }
    if (lane < NCLS) {
        float o = res[0];
#pragma unroll
        for (int c = 1; c < NCLS; c++) o = (lane == c) ? res[c] : o;
        hs2[(size_t)i * NCLS + lane] = dv * o;
    }
}

// ---- layer-2 aggregation (gather) + b2 + log_softmax ----
// 8 lanes per node; lanes 0..6 own classes.
__global__ __launch_bounds__(256) void k_agg2(const int* __restrict__ csr,
                                              const int* __restrict__ offs,
                                              const int* __restrict__ cnt,
                                              const float* __restrict__ dinv,
                                              const float* __restrict__ hs2,
                                              const float* __restrict__ b2,
                                              float* __restrict__ out, int N) {
    int lane = threadIdx.x & 7;
    int i = blockIdx.x * 32 + (threadIdx.x >> 3);
    if (i >= N) return;  // group-uniform
    int cc = lane < NCLS ? lane : NCLS - 1;
    int end = offs[i], cn = cnt[i], start = end - cn;
    float acc = hs2[(size_t)i * NCLS + cc];  // self-loop (pre-scaled)
    for (int k = start; k < end; k++) {
        int s = csr[k];
        acc += hs2[(size_t)s * NCLS + cc];
    }
    float v = fmaf(dinv[i], acc, b2[cc]);
    float vm = (lane < NCLS) ? v : -INFINITY;
    float m = vm;
#pragma unroll
    for (int w = 4; w >= 1; w >>= 1) m = fmaxf(m, __shfl_xor(m, w, 8));
    float e = (lane < NCLS) ? expf(v - m) : 0.0f;
    float ssum = e;
#pragma unroll
    for (int w = 4; w >= 1; w >>= 1) ssum += __shfl_xor(ssum, w, 8);
    if (lane < NCLS) out[(size_t)i * NCLS + lane] = v - m - logf(ssum);
}

extern "C" void kernel_launch(void* const* d_in, const int* in_sizes, int n_in,
                              void* d_out, int out_size, void* d_ws, size_t ws_size,
                              hipStream_t stream) {
    const float* x  = (const float*)d_in[0];
    const int*   ei = (const int*)d_in[1];
    const float* W1 = (const float*)d_in[2];
    const float* b1 = (const float*)d_in[3];
    const float* W2 = (const float*)d_in[4];
    const float* b2 = (const float*)d_in[5];
    float* out = (float*)d_out;

    const int N = in_sizes[0] / F_IN;  // 100000
    const int E = in_sizes[1] / 2;     // 3200000

    // ws layout (4B units): [cnt N][offs N][bsum 512][dinv N][hs1 16N][hs2 7N][csr E]
    int*   cnt  = (int*)d_ws;
    int*   offs = cnt + N;
    int*   bsum = offs + N;
    float* dinv = (float*)(bsum + 512);
    float* hs1  = dinv + N;
    float* hs2  = hs1 + (size_t)N * HID;
    int*   csr  = (int*)(hs2 + (size_t)N * NCLS);

    hipMemsetAsync(cnt, 0, (size_t)N * sizeof(int), stream);

    int bE = (E + 255) / 256;
    int bN = (N + 255) / 256;
    int nbScan = (N + 1023) / 1024;  // <=512

    k_deg<<<bE, 256, 0, stream>>>(ei, E, cnt);
    k_dinv<<<bN, 256, 0, stream>>>(cnt, dinv, N);
    k_gemm1<<<bN, 256, 0, stream>>>(x, W1, dinv, hs1, N);
    k_scan_a<<<nbScan, 256, 0, stream>>>(cnt, N, offs, bsum);
    k_scan_b<<<1, 512, 0, stream>>>(bsum, nbScan);
    k_scan_c<<<nbScan, 256, 0, stream>>>(offs, N, bsum);
    k_scatter<<<bE, 256, 0, stream>>>(ei, E, offs, csr);
    k_agg1<<<(N + 15) / 16, 256, 0, stream>>>(csr, offs, cnt, dinv, hs1, b1, W2, hs2, N);
    k_agg2<<<(N + 31) / 32, 256, 0, stream>>>(csr, offs, cnt, dinv, hs2, b2, out, N);
}

// Round 4
// 585.826 us; speedup vs baseline: 7.2325x; 1.4368x over previous
//
#include <hip/hip_runtime.h>
#include <math.h>

// GCN 2-layer, f32. N=100000, E=3200000, F_in=512, H=16, C=7.
// Round 4: CSR build with ZERO global atomics (two-phase bucket counting sort).
//   A1: per-chunk LDS histogram over buckets (dst>>8)
//   A2: column scan (chunk offsets per bucket) + bucket-base scan  [1 block]
//   A3: deterministic partition scatter, packed (dl<<24)|src, normal stores
//   B : per-bucket LDS counting sort -> csr, cnt, offs(row start), dinv
// Then: gemm1 (pre-scaled by dinv) -> agg1(+b1,relu,@W2,*dinv) -> agg2(+b2,log_softmax).

#define F_IN 512
#define HID  16
#define NCLS 7
#define NCHUNK 256
#define NBMAX 400   // LDS capacity for buckets; runtime nb = ceil(N/256) = 391
#define CAP 10240   // max edges per bucket held in LDS (mean ~8184, +22 sigma)

// ---- A1: per-chunk histogram over buckets ----
__global__ __launch_bounds__(256) void k_a1(const int* __restrict__ ei, int E, int perChunk,
                                            int nb, int* __restrict__ bh) {
    __shared__ int hist[NBMAX];
    for (int t = threadIdx.x; t < nb; t += 256) hist[t] = 0;
    __syncthreads();
    const int* dst = ei + E;
    int c = blockIdx.x;
    int s0 = c * perChunk;
    int s1 = min(s0 + perChunk, E);
    for (int e = s0 + threadIdx.x; e < s1; e += 256)
        atomicAdd(&hist[dst[e] >> 8], 1);
    __syncthreads();
    for (int t = threadIdx.x; t < nb; t += 256) bh[c * nb + t] = hist[t];
}

// ---- A2: per-bucket scan across chunks (in place) + bucket base scan ----
__global__ __launch_bounds__(512) void k_a2(int* __restrict__ bh, int nb,
                                            int* __restrict__ Tb, int* __restrict__ Bb) {
    __shared__ int sd[512];
    int tid = threadIdx.x;
    int acc = 0;
    if (tid < nb) {
#pragma unroll 4
        for (int c = 0; c < NCHUNK; c++) {
            int t = bh[c * nb + tid];
            bh[c * nb + tid] = acc;
            acc += t;
        }
    }
    sd[tid] = (tid < nb) ? acc : 0;
    __syncthreads();
    for (int off = 1; off < 512; off <<= 1) {
        int t = (tid >= off) ? sd[tid - off] : 0;
        __syncthreads();
        sd[tid] += t;
        __syncthreads();
    }
    if (tid < nb) { Tb[tid] = acc; Bb[tid] = sd[tid] - acc; }
}

// ---- A3: partition scatter (deterministic positions, LDS rank only) ----
__global__ __launch_bounds__(256) void k_a3(const int* __restrict__ ei, int E, int perChunk,
                                            int nb, const int* __restrict__ bh,
                                            const int* __restrict__ Bb,
                                            unsigned* __restrict__ part) {
    __shared__ int cur[NBMAX];
    __shared__ int baseL[NBMAX];
    int c = blockIdx.x;
    for (int t = threadIdx.x; t < nb; t += 256) {
        cur[t] = 0;
        baseL[t] = Bb[t] + bh[c * nb + t];
    }
    __syncthreads();
    const int* src = ei;
    const int* dst = ei + E;
    int s0 = c * perChunk;
    int s1 = min(s0 + perChunk, E);
    for (int e = s0 + threadIdx.x; e < s1; e += 256) {
        int s = src[e], d = dst[e];
        int b = d >> 8;
        int r = atomicAdd(&cur[b], 1);
        part[baseL[b] + r] = ((unsigned)(d & 255) << 24) | (unsigned)s;
    }
}

// ---- B: per-bucket counting sort -> csr, cnt, offs (row START), dinv ----
__global__ __launch_bounds__(256) void k_b(const unsigned* __restrict__ part,
                                           const int* __restrict__ Tb,
                                           const int* __restrict__ Bb,
                                           int* __restrict__ csr, int* __restrict__ cnt,
                                           int* __restrict__ offs, float* __restrict__ dinv,
                                           int N) {
    __shared__ unsigned eL[CAP];
    __shared__ int hist[256], cur[256], sd[256];
    int b = blockIdx.x, tid = threadIdx.x;
    int base = Bb[b], ct = Tb[b];
    hist[tid] = 0;
    __syncthreads();
    for (int k = tid; k < ct; k += 256) {
        unsigned v = part[base + k];
        if (k < CAP) eL[k] = v;
        atomicAdd(&hist[v >> 24], 1);
    }
    __syncthreads();
    int h = hist[tid];
    sd[tid] = h;
    __syncthreads();
    for (int off = 1; off < 256; off <<= 1) {
        int t = (tid >= off) ? sd[tid - off] : 0;
        __syncthreads();
        sd[tid] += t;
        __syncthreads();
    }
    int ex = sd[tid] - h;
    cur[tid] = ex;
    int node = (b << 8) + tid;
    if (node < N) {
        cnt[node] = h;
        offs[node] = base + ex;
        dinv[node] = rsqrtf((float)h + 1.0f);
    }
    __syncthreads();
    for (int k = tid; k < ct; k += 256) {
        unsigned v = (k < CAP) ? eL[k] : part[base + k];
        int dl = (int)(v >> 24);
        int r = atomicAdd(&cur[dl], 1);
        csr[base + r] = (int)(v & 0xFFFFFFu);
    }
}

// ---- hs1[i][j] = dinv[i] * sum_k x[i][k]*W1[k][j]; W1 in LDS broadcast ----
__global__ __launch_bounds__(256) void k_gemm1(const float* __restrict__ x,
                                               const float* __restrict__ W1,
                                               const float* __restrict__ dinv,
                                               float* __restrict__ hs1, int N) {
    __shared__ float wl[F_IN * HID];  // 32 KB
    for (int t = threadIdx.x; t < F_IN * HID; t += 256) wl[t] = W1[t];
    __syncthreads();
    int row = blockIdx.x * blockDim.x + threadIdx.x;
    if (row >= N) return;
    const float* xr = x + (size_t)row * F_IN;
    float acc[HID];
#pragma unroll
    for (int j = 0; j < HID; j++) acc[j] = 0.0f;
    for (int k0 = 0; k0 < F_IN; k0 += 4) {
        float4 xv = *(const float4*)(xr + k0);
        const float* w0 = &wl[k0 * HID];
#pragma unroll
        for (int j = 0; j < HID; j++) acc[j] = fmaf(xv.x, w0[j], acc[j]);
#pragma unroll
        for (int j = 0; j < HID; j++) acc[j] = fmaf(xv.y, w0[HID + j], acc[j]);
#pragma unroll
        for (int j = 0; j < HID; j++) acc[j] = fmaf(xv.z, w0[2 * HID + j], acc[j]);
#pragma unroll
        for (int j = 0; j < HID; j++) acc[j] = fmaf(xv.w, w0[3 * HID + j], acc[j]);
    }
    float dv = dinv[row];
    float* hr = hs1 + (size_t)row * HID;
#pragma unroll
    for (int j = 0; j < HID; j += 4)
        *(float4*)(hr + j) = make_float4(dv * acc[j], dv * acc[j + 1],
                                         dv * acc[j + 2], dv * acc[j + 3]);
}

// ---- layer-1 gather + b1 + relu + @W2 + *dinv -> hs2. 16 lanes/node ----
__global__ __launch_bounds__(256) void k_agg1(const int* __restrict__ csr,
                                              const int* __restrict__ offs,
                                              const int* __restrict__ cnt,
                                              const float* __restrict__ dinv,
                                              const float* __restrict__ hs1,
                                              const float* __restrict__ b1,
                                              const float* __restrict__ W2,
                                              float* __restrict__ hs2, int N) {
    int lane = threadIdx.x & 15;
    int i = blockIdx.x * 16 + (threadIdx.x >> 4);
    float w2r[NCLS];
#pragma unroll
    for (int c = 0; c < NCLS; c++) w2r[c] = W2[lane * NCLS + c];
    float b1l = b1[lane];
    if (i >= N) return;  // group-uniform
    int start = offs[i], end = start + cnt[i];
    float acc = hs1[(size_t)i * HID + lane];  // self-loop (pre-scaled)
    for (int k = start; k < end; k++) {
        int s = csr[k];
        acc += hs1[(size_t)s * HID + lane];
    }
    float v = fmaf(dinv[i], acc, b1l);
    float hr = v > 0.0f ? v : 0.0f;
    float dv = dinv[i];
    float res[NCLS];
#pragma unroll
    for (int c = 0; c < NCLS; c++) {
        float t = hr * w2r[c];
#pragma unroll
        for (int w = 8; w >= 1; w >>= 1) t += __shfl_xor(t, w, 16);
        res[c] = t;
    }
    if (lane < NCLS) {
        float o = res[0];
#pragma unroll
        for (int c = 1; c < NCLS; c++) o = (lane == c) ? res[c] : o;
        hs2[(size_t)i * NCLS + lane] = dv * o;
    }
}

// ---- layer-2 gather + b2 + log_softmax. 8 lanes/node ----
__global__ __launch_bounds__(256) void k_agg2(const int* __restrict__ csr,
                                              const int* __restrict__ offs,
                                              const int* __restrict__ cnt,
                                              const float* __restrict__ dinv,
                                              const float* __restrict__ hs2,
                                              const float* __restrict__ b2,
                                              float* __restrict__ out, int N) {
    int lane = threadIdx.x & 7;
    int i = blockIdx.x * 32 + (threadIdx.x >> 3);
    if (i >= N) return;  // group-uniform
    int cc = lane < NCLS ? lane : NCLS - 1;
    int start = offs[i], end = start + cnt[i];
    float acc = hs2[(size_t)i * NCLS + cc];  // self-loop (pre-scaled)
    for (int k = start; k < end; k++) {
        int s = csr[k];
        acc += hs2[(size_t)s * NCLS + cc];
    }
    float v = fmaf(dinv[i], acc, b2[cc]);
    float vm = (lane < NCLS) ? v : -INFINITY;
    float m = vm;
#pragma unroll
    for (int w = 4; w >= 1; w >>= 1) m = fmaxf(m, __shfl_xor(m, w, 8));
    float e = (lane < NCLS) ? expf(v - m) : 0.0f;
    float ssum = e;
#pragma unroll
    for (int w = 4; w >= 1; w >>= 1) ssum += __shfl_xor(ssum, w, 8);
    if (lane < NCLS) out[(size_t)i * NCLS + lane] = v - m - logf(ssum);
}

extern "C" void kernel_launch(void* const* d_in, const int* in_sizes, int n_in,
                              void* d_out, int out_size, void* d_ws, size_t ws_size,
                              hipStream_t stream) {
    const float* x  = (const float*)d_in[0];
    const int*   ei = (const int*)d_in[1];
    const float* W1 = (const float*)d_in[2];
    const float* b1 = (const float*)d_in[3];
    const float* W2 = (const float*)d_in[4];
    const float* b2 = (const float*)d_in[5];
    float* out = (float*)d_out;

    const int N = in_sizes[0] / F_IN;   // 100000
    const int E = in_sizes[1] / 2;      // 3200000
    const int nb = (N + 255) >> 8;      // 391 buckets
    const int perChunk = (E + NCHUNK - 1) / NCHUNK;  // 12500

    // ws layout (4B units):
    // [bh NCHUNK*nb][Tb nb][Bb nb][part E][csr E][cnt N][offs N][dinv N][hs1 16N][hs2 7N]
    int*      bh   = (int*)d_ws;
    int*      Tb   = bh + (size_t)NCHUNK * nb;
    int*      Bb   = Tb + nb;
    unsigned* part = (unsigned*)(Bb + nb);
    int*      csr  = (int*)(part + E);
    int*      cnt  = csr + E;
    int*      offs = cnt + N;
    float*    dinv = (float*)(offs + N);
    float*    hs1  = dinv + N;
    float*    hs2  = hs1 + (size_t)N * HID;

    k_a1<<<NCHUNK, 256, 0, stream>>>(ei, E, perChunk, nb, bh);
    k_a2<<<1, 512, 0, stream>>>(bh, nb, Tb, Bb);
    k_a3<<<NCHUNK, 256, 0, stream>>>(ei, E, perChunk, nb, bh, Bb, part);
    k_b<<<nb, 256, 0, stream>>>(part, Tb, Bb, csr, cnt, offs, dinv, N);
    k_gemm1<<<(N + 255) / 256, 256, 0, stream>>>(x, W1, dinv, hs1, N);
    k_agg1<<<(N + 15) / 16, 256, 0, stream>>>(csr, offs, cnt, dinv, hs1, b1, W2, hs2, N);
    k_agg2<<<(N + 31) / 32, 256, 0, stream>>>(csr, offs, cnt, dinv, hs2, b2, out, N);
}